// Round 3
// baseline (245.347 us; speedup 1.0000x reference)
//
#include <hip/hip_runtime.h>
#include <hip/hip_cooperative_groups.h>
#include <math.h>

namespace cg = cooperative_groups;

// Gaussian KDE, n=12000, fused single cooperative kernel.
// Grid = IB*YW blocks (47*16=752), 256 threads. Each block: 256 i's (II=4 per
// thread) x one j-window of WIN=752 elements.
//   A: rank counts (lt/le packed) per (i, window) + per-window stats partials
//   B: (16 blocks) sum packed counts over windows, pick 4 order-stat values
//   C: per-block h recompute (cheap, fp32 transcendentals, fp64 sums);
//      KDE pass: acc += w'_j * exp2(-(e_i-e_j)^2)
//   D: (47 blocks) out[i] = log(sum_y partial + 1e-10)
// All cross-block sums are fixed-order -> bit-deterministic.

#define YW 16
#define MAXWIN 1024
#define BLK 256

#if defined(__has_builtin)
#if __has_builtin(__builtin_amdgcn_exp2f)
#define EXP2(x) __builtin_amdgcn_exp2f(x)
#endif
#endif
#ifndef EXP2
#define EXP2(x) exp2f(x)
#endif

__global__ __launch_bounds__(BLK, 3) void fused_k(
    const float* __restrict__ d, const float* __restrict__ w,
    float* __restrict__ out, float* __restrict__ wsf, int n, int nmax, int IB) {
    cg::grid_group grid = cg::this_grid();

    __shared__ float4 smem4[MAXWIN / 2];  // 8 KB, reused per phase
    __shared__ float4 sstat[4];
    __shared__ float sparam[2];

    float* qv      = wsf;                      // [4]
    float* statsP  = wsf + 16;                 // float4[YW]
    int*   counts  = (int*)(wsf + 256);        // [YW*nmax]
    float* partial = wsf + 256 + YW * nmax;    // [YW*nmax]

    const int t = threadIdx.x, b = blockIdx.x;
    const int ib = b % IB, y = b / IB;
    const int lane = t & 63, wv = t >> 6;
    const int WIN = nmax / YW;
    const int WQ = WIN >> 2;
    const int j0 = y * WIN;

    // rank targets (torch/jnp linear-interp quantile)
    const double p25 = 0.25 * (double)(n - 1);
    const double p75 = 0.75 * (double)(n - 1);
    const int l25 = (int)p25, l75 = (int)p75;
    const int u25 = (l25 + 1 < n) ? l25 + 1 : l25;
    const int u75 = (l75 + 1 < n) ? l75 + 1 : l75;

    float* sd = (float*)smem4;

    // ---------------- phase A: counts + stats ----------------
    for (int idx = t; idx < WIN; idx += BLK) {
        int jg = j0 + idx;
        sd[idx] = (jg < n) ? d[jg] : __int_as_float(0x7f800000);  // +inf pad
    }
    float di0, di1, di2, di3;
    {
        int i0 = ib * 256 + lane;
        di0 = (i0       < n) ? d[i0]       : 0.f;
        di1 = (i0 + 64  < n) ? d[i0 + 64]  : 0.f;
        di2 = (i0 + 128 < n) ? d[i0 + 128] : 0.f;
        di3 = (i0 + 192 < n) ? d[i0 + 192] : 0.f;
    }
    __syncthreads();
    int lt0 = 0, le0 = 0, lt1 = 0, le1 = 0, lt2 = 0, le2 = 0, lt3 = 0, le3 = 0;
    {
        const float4* p4 = (const float4*)(sd + wv * WQ);
        const int nq = WQ >> 2;
        for (int jj = 0; jj < nq; ++jj) {
            float4 q = p4[jj];
            lt0 += q.x < di0; le0 += q.x <= di0;
            lt0 += q.y < di0; le0 += q.y <= di0;
            lt0 += q.z < di0; le0 += q.z <= di0;
            lt0 += q.w < di0; le0 += q.w <= di0;
            lt1 += q.x < di1; le1 += q.x <= di1;
            lt1 += q.y < di1; le1 += q.y <= di1;
            lt1 += q.z < di1; le1 += q.z <= di1;
            lt1 += q.w < di1; le1 += q.w <= di1;
            lt2 += q.x < di2; le2 += q.x <= di2;
            lt2 += q.y < di2; le2 += q.y <= di2;
            lt2 += q.z < di2; le2 += q.z <= di2;
            lt2 += q.w < di2; le2 += q.w <= di2;
            lt3 += q.x < di3; le3 += q.x <= di3;
            lt3 += q.y < di3; le3 += q.y <= di3;
            lt3 += q.z < di3; le3 += q.z <= di3;
            lt3 += q.w < di3; le3 += q.w <= di3;
        }
    }
    float4 st = make_float4(0.f, 0.f, 0.f, 0.f);
    if (ib == 0) {  // one block per window does stats partials
        for (int idx = t; idx < WIN; idx += BLK) {
            int jg = j0 + idx;
            if (jg < n) {
                float dv = sd[idx], wj = w[jg];
                st.x += wj; st.y += wj * wj; st.z += dv; st.w += dv * dv;
            }
        }
    }
    __syncthreads();  // sd consumed
    {
        int* arr = (int*)smem4;
        arr[wv * 256 +       lane] = (le0 << 16) | lt0;
        arr[wv * 256 +  64 + lane] = (le1 << 16) | lt1;
        arr[wv * 256 + 128 + lane] = (le2 << 16) | lt2;
        arr[wv * 256 + 192 + lane] = (le3 << 16) | lt3;
        __syncthreads();
        counts[y * nmax + ib * 256 + t] =
            arr[t] + arr[256 + t] + arr[512 + t] + arr[768 + t];
    }
    if (ib == 0) {
        for (int off = 32; off > 0; off >>= 1) {
            st.x += __shfl_down(st.x, off); st.y += __shfl_down(st.y, off);
            st.z += __shfl_down(st.z, off); st.w += __shfl_down(st.w, off);
        }
        if (lane == 0) sstat[wv] = st;
        __syncthreads();
        if (t == 0) {
            float4 a = sstat[0], b4 = sstat[1], c4 = sstat[2], e4 = sstat[3];
            ((float4*)statsP)[y] = make_float4(a.x + b4.x + c4.x + e4.x,
                                               a.y + b4.y + c4.y + e4.y,
                                               a.z + b4.z + c4.z + e4.z,
                                               a.w + b4.w + c4.w + e4.w);
        }
    }

    grid.sync();  // #1

    // ---------------- phase B: quantile candidates ----------------
    if (b < YW) {
        for (int i = b * 256 + t; i < n; i += YW * 256) {
            int c = 0;
            #pragma unroll
            for (int y2 = 0; y2 < YW; ++y2) c += counts[y2 * nmax + i];
            int lt = c & 0xFFFF, le = c >> 16;
            float dv = d[i];
            if (lt <= l25 && l25 < le) qv[0] = dv;
            if (lt <= u25 && u25 < le) qv[1] = dv;
            if (lt <= l75 && l75 < le) qv[2] = dv;
            if (lt <= u75 && u75 < le) qv[3] = dv;
        }
    }

    grid.sync();  // #2

    // ---------------- phase C: h + KDE ----------------
    if (t == 0) {
        double S1 = 0, S2 = 0, Sd = 0, Sd2 = 0;
        for (int k = 0; k < YW; ++k) {
            float4 v = ((float4*)statsP)[k];
            S1 += v.x; S2 += v.y; Sd += v.z; Sd2 += v.w;
        }
        float neff = (float)(S1 * S1 / S2);
        float var  = (float)((Sd2 - Sd * Sd / (double)n) / (double)(n - 1));
        float sdev = sqrtf(var);
        float f25 = (float)(p25 - (double)l25), f75 = (float)(p75 - (double)l75);
        float q25 = qv[0] + f25 * (qv[1] - qv[0]);
        float q75 = qv[2] + f75 * (qv[3] - qv[2]);
        float iqr = q75 - q25;
        float sig = fminf(sdev, iqr * (1.0f / 1.34f));
        float h = 0.9f * sig * exp2f(-0.2f * log2f(neff));
        sparam[0] = 0.84932175f / h;                       // sqrt(0.5*log2(e))/h
        sparam[1] = 1.0f / (h * 2.5066282746f * (float)S1); // inv_norm / S1
    }
    __syncthreads();
    const float r = sparam[0], wsc = sparam[1];
    float2* sj = (float2*)smem4;
    for (int idx = t; idx < WIN; idx += BLK) {
        int jg = j0 + idx;
        sj[idx] = (jg < n) ? make_float2(d[jg] * r, w[jg] * wsc)
                           : make_float2(0.f, 0.f);  // w=0 pad: no contribution
    }
    const float e0 = di0 * r, e1 = di1 * r, e2 = di2 * r, e3 = di3 * r;
    __syncthreads();
    float a0 = 0.f, a1 = 0.f, a2 = 0.f, a3 = 0.f;
    {
        const float4* pj = (const float4*)(sj + wv * WQ);  // (e,w,e,w)
        const int nq = WQ >> 1;
        for (int jj = 0; jj < nq; ++jj) {
            float4 q = pj[jj];
            { float u = e0 - q.x, v = e0 - q.z;
              a0 = fmaf(q.y, EXP2(-(u * u)), a0); a0 = fmaf(q.w, EXP2(-(v * v)), a0); }
            { float u = e1 - q.x, v = e1 - q.z;
              a1 = fmaf(q.y, EXP2(-(u * u)), a1); a1 = fmaf(q.w, EXP2(-(v * v)), a1); }
            { float u = e2 - q.x, v = e2 - q.z;
              a2 = fmaf(q.y, EXP2(-(u * u)), a2); a2 = fmaf(q.w, EXP2(-(v * v)), a2); }
            { float u = e3 - q.x, v = e3 - q.z;
              a3 = fmaf(q.y, EXP2(-(u * u)), a3); a3 = fmaf(q.w, EXP2(-(v * v)), a3); }
        }
    }
    __syncthreads();  // sj consumed
    {
        float* farr = (float*)smem4;
        farr[wv * 256 +       lane] = a0;
        farr[wv * 256 +  64 + lane] = a1;
        farr[wv * 256 + 128 + lane] = a2;
        farr[wv * 256 + 192 + lane] = a3;
        __syncthreads();
        partial[y * nmax + ib * 256 + t] =
            farr[t] + farr[256 + t] + farr[512 + t] + farr[768 + t];
    }

    grid.sync();  // #3

    // ---------------- phase D: finalize ----------------
    if (b < IB) {
        int i = b * 256 + t;
        if (i < n) {
            float p = 0.f;
            #pragma unroll
            for (int y2 = 0; y2 < YW; ++y2) p += partial[y2 * nmax + i];
            out[i] = logf(p + 1e-10f);
        }
    }
}

// ======================= fallback path (R2, known-good) =======================
#define MAXJC 752

__global__ __launch_bounds__(BLK) void count_k(const float* __restrict__ d,
                                               int* __restrict__ counts,
                                               int n, int JC, int nmax) {
    __shared__ float sd_[4 * MAXJC];
    const int t = threadIdx.x;
    const int win = 4 * JC;
    const int jwin0 = blockIdx.y * win;
    for (int idx = t; idx < win; idx += BLK) {
        int jg = jwin0 + idx;
        sd_[idx] = (jg < n) ? d[jg] : __int_as_float(0x7f800000);
    }
    __syncthreads();
    const int lane = t & 63, c4 = t >> 6;
    const int i = blockIdx.x * 64 + lane;
    const float di = (i < n) ? d[i] : 0.f;
    int lt = 0, eq = 0;
    const float4* p4 = (const float4*)(sd_ + c4 * JC);
    const int nq = JC >> 2;
    for (int jj = 0; jj < nq; ++jj) {
        float4 q = p4[jj];
        lt += (q.x < di) + (q.y < di) + (q.z < di) + (q.w < di);
        eq += (q.x == di) + (q.y == di) + (q.z == di) + (q.w == di);
    }
    __syncthreads();
    int* red = (int*)sd_;
    red[t] = (lt << 16) | eq;
    __syncthreads();
    if (t < 64 && i < n) {
        int s = red[t] + red[t + 64] + red[t + 128] + red[t + 192];
        counts[blockIdx.y * nmax + blockIdx.x * 64 + t] = s;
    }
}

__global__ __launch_bounds__(1024) void pick_k(const float* __restrict__ d,
                                               const float* __restrict__ w,
                                               const int* __restrict__ counts,
                                               float2* __restrict__ ejwj,
                                               int n, int nmax) {
    __shared__ float sp[4];
    __shared__ float sparams[2];
    __shared__ float4 sred[16];
    const int t = threadIdx.x;

    const double p25 = 0.25 * (double)(n - 1);
    const double p75 = 0.75 * (double)(n - 1);
    const int l25 = (int)p25, l75 = (int)p75;
    const int u25 = (l25 + 1 < n) ? l25 + 1 : l25;
    const int u75 = (l75 + 1 < n) ? l75 + 1 : l75;

    float s1 = 0.f, s2 = 0.f, sd = 0.f, sd2 = 0.f;
    for (int i = t; i < n; i += 1024) {
        float wv = w[i], dv = d[i];
        s1 += wv; s2 += wv * wv; sd += dv; sd2 += dv * dv;
        int c = counts[i] + counts[nmax + i] + counts[2 * nmax + i] + counts[3 * nmax + i];
        int lt = c >> 16, eq = c & 0xFFFF;
        int hi = lt + eq;
        if (lt <= l25 && l25 < hi) sp[0] = dv;
        if (lt <= u25 && u25 < hi) sp[1] = dv;
        if (lt <= l75 && l75 < hi) sp[2] = dv;
        if (lt <= u75 && u75 < hi) sp[3] = dv;
    }
    for (int off = 32; off > 0; off >>= 1) {
        s1  += __shfl_down(s1,  off);
        s2  += __shfl_down(s2,  off);
        sd  += __shfl_down(sd,  off);
        sd2 += __shfl_down(sd2, off);
    }
    const int wid = t >> 6, lane = t & 63;
    if (lane == 0) sred[wid] = make_float4(s1, s2, sd, sd2);
    __syncthreads();
    if (t == 0) {
        float4 a = sred[0];
        for (int k = 1; k < 16; ++k) {
            a.x += sred[k].x; a.y += sred[k].y; a.z += sred[k].z; a.w += sred[k].w;
        }
        double S1 = a.x, S2 = a.y, Sd = a.z, Sd2 = a.w;
        double neff = S1 * S1 / S2;
        double var  = (Sd2 - Sd * Sd / (double)n) / ((double)n - 1.0);
        double sdev = sqrt(var);
        double f25 = p25 - (double)l25, f75 = p75 - (double)l75;
        double q25 = (double)sp[0] + f25 * ((double)sp[1] - (double)sp[0]);
        double q75 = (double)sp[2] + f75 * ((double)sp[3] - (double)sp[2]);
        double iqr = q75 - q25;
        double sig = fmin(sdev, iqr / 1.34);
        double h = 0.9 * sig * pow(neff, -0.2);
        double r = sqrt(0.5 * 1.4426950408889634) / h;
        double wsc = 1.0 / (h * sqrt(6.283185307179586) * S1);
        sparams[0] = (float)r;
        sparams[1] = (float)wsc;
    }
    __syncthreads();
    const float r = sparams[0], wsc = sparams[1];
    for (int j = t; j < n; j += 1024)
        ejwj[j] = make_float2(d[j] * r, w[j] * wsc);
}

__global__ __launch_bounds__(BLK) void kde_k(const float2* __restrict__ ejwj,
                                             float* __restrict__ partial,
                                             int n, int JC, int nmax) {
    __shared__ float2 sj[4 * MAXJC];
    const int t = threadIdx.x;
    const int win = 4 * JC;
    const int jwin0 = blockIdx.y * win;
    for (int idx = t; idx < win; idx += BLK) {
        int jg = jwin0 + idx;
        sj[idx] = (jg < n) ? ejwj[jg] : make_float2(0.f, 0.f);
    }
    __syncthreads();
    const int lane = t & 63, c4 = t >> 6;
    const int i = blockIdx.x * 64 + lane;
    const float ei = (i < n) ? ejwj[i].x : 0.f;
    const float4* p4 = (const float4*)(sj + c4 * JC);
    float acc0 = 0.f, acc1 = 0.f;
    const int nq = JC >> 1;
    for (int jj = 0; jj < nq; ++jj) {
        float4 q = p4[jj];
        float da = ei - q.x;
        float db = ei - q.z;
        acc0 += q.y * EXP2(-(da * da));
        acc1 += q.w * EXP2(-(db * db));
    }
    __syncthreads();
    float* red = (float*)sj;
    red[t] = acc0 + acc1;
    __syncthreads();
    if (t < 64) {
        int ii = blockIdx.x * 64 + t;
        if (ii < n) {
            float s = red[t] + red[t + 64] + red[t + 128] + red[t + 192];
            partial[blockIdx.y * nmax + ii] = s;
        }
    }
}

__global__ void fin_k(const float* __restrict__ partial, float* __restrict__ out,
                      int n, int nmax) {
    int i = blockIdx.x * blockDim.x + threadIdx.x;
    if (i < n) {
        float p = partial[i] + partial[nmax + i] + partial[2 * nmax + i] + partial[3 * nmax + i];
        out[i] = logf(p + 1e-10f);
    }
}

extern "C" void kernel_launch(void* const* d_in, const int* in_sizes, int n_in,
                              void* d_out, int out_size, void* d_ws, size_t ws_size,
                              hipStream_t stream) {
    const float* d = (const float*)d_in[0];
    const float* w = (const float*)d_in[1];
    float* out = (float*)d_out;
    int n = in_sizes[0];

    int nmax = ((n + 255) / 256) * 256;  // 12032
    int IB = nmax / 256;                 // 47
    float* wsf = (float*)d_ws;

    void* args[] = {(void*)&d, (void*)&w, (void*)&out, (void*)&wsf,
                    (void*)&n, (void*)&nmax, (void*)&IB};
    hipError_t rc = hipLaunchCooperativeKernel((const void*)fused_k,
                                               dim3(IB * YW), dim3(BLK),
                                               args, 0, stream);
    if (rc != hipSuccess) {
        // fallback: 4-kernel path
        int nmax64 = ((n + 63) / 64) * 64;   // 12032
        int JC     = 4 * ((n + 63) / 64);    // 752
        int*   counts  = (int*)wsf;
        float2* ejwj   = (float2*)(wsf + 4 * nmax64);
        float* partial = wsf + 6 * nmax64;
        dim3 grid(nmax64 / 64, 4);
        count_k<<<grid, BLK, 0, stream>>>(d, counts, n, JC, nmax64);
        pick_k<<<1, 1024, 0, stream>>>(d, w, counts, ejwj, n, nmax64);
        kde_k<<<grid, BLK, 0, stream>>>(ejwj, partial, n, JC, nmax64);
        fin_k<<<(n + 255) / 256, 256, 0, stream>>>(partial, out, n, nmax64);
    }
}

// Round 4
// 82.538 us; speedup vs baseline: 2.9725x; 2.9725x over previous
//
#include <hip/hip_runtime.h>
#include <math.h>

// Gaussian KDE, n=12000. 3 dispatches, no grid.sync, no memset, no float atomics.
//   1) count_k  grid(47,16)x256: block = 256 i's (II=4/lane) x 752-j window.
//      counts[y*nmax+i] = packed (le<<16|lt) partial; ib==0 blocks also emit
//      per-window stats partials (S1,S2,Sd,Sd2).
//   2) pick_k   1x1024: sum 16 packed count partials -> 4 order stats; h, r, wsc;
//      writes ejwj[] (pre-scaled); zeroes the done-counter for kdefin.
//   3) kdefin_k grid(47,16)x256: partial[y*nmax+i] = sum_{j in win} w'_j*exp2(-(e_i-e_j)^2)
//      (II=4). Last block to finish (device atomic counter) sums the 16 window
//      partials in fixed order and writes out[i] = log(pdf+1e-10).
// All accumulation orders are fixed -> bit-deterministic across replays.

#define BLK 256
#define YW 16
#define MAXWIN 768

#if defined(__has_builtin)
#if __has_builtin(__builtin_amdgcn_exp2f)
#define EXP2(x) __builtin_amdgcn_exp2f(x)
#endif
#endif
#ifndef EXP2
#define EXP2(x) exp2f(x)
#endif

__global__ __launch_bounds__(BLK) void count_k(const float* __restrict__ d,
                                               const float* __restrict__ w,
                                               int* __restrict__ counts,
                                               float4* __restrict__ statsP,
                                               int n, int nmax) {
    __shared__ int smem[1024];          // phase1: float window[752]; phase2: int[1024] combine
    __shared__ float4 sstat[4];
    const int t = threadIdx.x, ib = blockIdx.x, y = blockIdx.y;
    const int lane = t & 63, wv = t >> 6;
    const int WIN = nmax / YW;          // 752
    const int j0 = y * WIN;

    float* sd = (float*)smem;
    for (int idx = t; idx < WIN; idx += BLK) {
        int jg = j0 + idx;
        sd[idx] = (jg < n) ? d[jg] : __int_as_float(0x7f800000);  // +inf pad: <, <= false
    }
    const int i0 = ib * 256 + lane;
    const float di0 = (i0       < n) ? d[i0]       : 0.f;
    const float di1 = (i0 + 64  < n) ? d[i0 + 64]  : 0.f;
    const float di2 = (i0 + 128 < n) ? d[i0 + 128] : 0.f;
    const float di3 = (i0 + 192 < n) ? d[i0 + 192] : 0.f;
    __syncthreads();

    int lt0 = 0, le0 = 0, lt1 = 0, le1 = 0, lt2 = 0, le2 = 0, lt3 = 0, le3 = 0;
    {
        const float4* p4 = (const float4*)(sd + wv * (WIN >> 2));  // 188 floats, 16B-aligned
        const int nq = WIN >> 4;  // 47
        for (int jj = 0; jj < nq; ++jj) {
            float4 q = p4[jj];
            lt0 += (q.x <  di0) + (q.y <  di0) + (q.z <  di0) + (q.w <  di0);
            le0 += (q.x <= di0) + (q.y <= di0) + (q.z <= di0) + (q.w <= di0);
            lt1 += (q.x <  di1) + (q.y <  di1) + (q.z <  di1) + (q.w <  di1);
            le1 += (q.x <= di1) + (q.y <= di1) + (q.z <= di1) + (q.w <= di1);
            lt2 += (q.x <  di2) + (q.y <  di2) + (q.z <  di2) + (q.w <  di2);
            le2 += (q.x <= di2) + (q.y <= di2) + (q.z <= di2) + (q.w <= di2);
            lt3 += (q.x <  di3) + (q.y <  di3) + (q.z <  di3) + (q.w <  di3);
            le3 += (q.x <= di3) + (q.y <= di3) + (q.z <= di3) + (q.w <= di3);
        }
    }
    // stats partials for this window (ib==0 blocks only), while sd still holds d
    float4 st = make_float4(0.f, 0.f, 0.f, 0.f);
    if (ib == 0) {
        for (int idx = t; idx < WIN; idx += BLK) {
            int jg = j0 + idx;
            if (jg < n) {
                float dv = sd[idx], wj = w[jg];
                st.x += wj; st.y += wj * wj; st.z += dv; st.w += dv * dv;
            }
        }
    }
    __syncthreads();  // sd consumed; reuse smem as int combine buffer
    smem[wv * 256 +       lane] = (le0 << 16) | lt0;
    smem[wv * 256 +  64 + lane] = (le1 << 16) | lt1;
    smem[wv * 256 + 128 + lane] = (le2 << 16) | lt2;
    smem[wv * 256 + 192 + lane] = (le3 << 16) | lt3;
    __syncthreads();
    counts[y * nmax + ib * 256 + t] =
        smem[t] + smem[256 + t] + smem[512 + t] + smem[768 + t];

    if (ib == 0) {
        for (int off = 32; off > 0; off >>= 1) {
            st.x += __shfl_down(st.x, off); st.y += __shfl_down(st.y, off);
            st.z += __shfl_down(st.z, off); st.w += __shfl_down(st.w, off);
        }
        if (lane == 0) sstat[wv] = st;
        __syncthreads();
        if (t == 0) {
            float4 a = sstat[0], b = sstat[1], c = sstat[2], e = sstat[3];
            statsP[y] = make_float4(a.x + b.x + c.x + e.x, a.y + b.y + c.y + e.y,
                                    a.z + b.z + c.z + e.z, a.w + b.w + c.w + e.w);
        }
    }
}

__global__ __launch_bounds__(1024) void pick_k(const float* __restrict__ d,
                                               const float* __restrict__ w,
                                               const int* __restrict__ counts,
                                               const float4* __restrict__ statsP,
                                               float2* __restrict__ ejwj,
                                               int* __restrict__ done,
                                               int n, int nmax) {
    __shared__ float sp[4];
    __shared__ float sparams[2];
    const int t = threadIdx.x;

    const double p25 = 0.25 * (double)(n - 1);
    const double p75 = 0.75 * (double)(n - 1);
    const int l25 = (int)p25, l75 = (int)p75;
    const int u25 = (l25 + 1 < n) ? l25 + 1 : l25;
    const int u75 = (l75 + 1 < n) ? l75 + 1 : l75;

    for (int i = t; i < n; i += 1024) {
        int c = 0;
        #pragma unroll
        for (int y = 0; y < YW; ++y) c += counts[y * nmax + i];
        int lt = c & 0xFFFF, le = c >> 16;   // le,lt <= nmax < 2^16: no cross-carry
        float dv = d[i];
        if (lt <= l25 && l25 < le) sp[0] = dv;
        if (lt <= u25 && u25 < le) sp[1] = dv;
        if (lt <= l75 && l75 < le) sp[2] = dv;
        if (lt <= u75 && u75 < le) sp[3] = dv;
    }
    __syncthreads();
    if (t == 0) {
        double S1 = 0, S2 = 0, Sd = 0, Sd2 = 0;
        for (int k = 0; k < YW; ++k) {
            float4 v = statsP[k];
            S1 += v.x; S2 += v.y; Sd += v.z; Sd2 += v.w;
        }
        double neff = S1 * S1 / S2;
        double var  = (Sd2 - Sd * Sd / (double)n) / ((double)n - 1.0);
        double sdev = sqrt(var);
        double f25 = p25 - (double)l25, f75 = p75 - (double)l75;
        double q25 = (double)sp[0] + f25 * ((double)sp[1] - (double)sp[0]);
        double q75 = (double)sp[2] + f75 * ((double)sp[3] - (double)sp[2]);
        double sig = fmin(sdev, (q75 - q25) / 1.34);
        double h = 0.9 * sig * pow(neff, -0.2);
        sparams[0] = (float)(sqrt(0.5 * 1.4426950408889634) / h);          // r
        sparams[1] = (float)(1.0 / (h * sqrt(6.283185307179586) * S1));    // wsc
        *done = 0;   // reset completion counter for kdefin_k (this launch)
    }
    __syncthreads();
    const float r = sparams[0], wsc = sparams[1];
    for (int j = t; j < nmax; j += 1024)
        ejwj[j] = (j < n) ? make_float2(d[j] * r, w[j] * wsc) : make_float2(0.f, 0.f);
}

__global__ __launch_bounds__(BLK) void kdefin_k(const float2* __restrict__ ejwj,
                                                float* __restrict__ partial,
                                                float* __restrict__ out,
                                                int* __restrict__ done,
                                                int n, int nmax) {
    __shared__ float2 sj[MAXWIN];    // 6 KB
    __shared__ float sredf[1024];    // 4 KB
    __shared__ int slast;
    const int t = threadIdx.x, ib = blockIdx.x, y = blockIdx.y;
    const int lane = t & 63, wv = t >> 6;
    const int WIN = nmax / YW;       // 752
    const int j0 = y * WIN;

    for (int idx = t; idx < WIN; idx += BLK)
        sj[idx] = ejwj[j0 + idx];    // pads already (0,0): zero weight
    const int i0 = ib * 256 + lane;
    const float ei0 = ejwj[i0].x;
    const float ei1 = ejwj[i0 + 64].x;
    const float ei2 = ejwj[i0 + 128].x;
    const float ei3 = ejwj[i0 + 192].x;
    __syncthreads();

    float a0 = 0.f, a1 = 0.f, a2 = 0.f, a3 = 0.f;
    {
        const float4* pj = (const float4*)(sj + wv * (WIN >> 2));  // 188 float2, 16B-aligned
        const int nq = WIN >> 3;  // 94 float4 = 188 j's
        for (int jj = 0; jj < nq; ++jj) {
            float4 q = pj[jj];  // (e_a, w_a, e_b, w_b)
            { float u = ei0 - q.x, v = ei0 - q.z;
              a0 = fmaf(q.y, EXP2(-(u * u)), a0); a0 = fmaf(q.w, EXP2(-(v * v)), a0); }
            { float u = ei1 - q.x, v = ei1 - q.z;
              a1 = fmaf(q.y, EXP2(-(u * u)), a1); a1 = fmaf(q.w, EXP2(-(v * v)), a1); }
            { float u = ei2 - q.x, v = ei2 - q.z;
              a2 = fmaf(q.y, EXP2(-(u * u)), a2); a2 = fmaf(q.w, EXP2(-(v * v)), a2); }
            { float u = ei3 - q.x, v = ei3 - q.z;
              a3 = fmaf(q.y, EXP2(-(u * u)), a3); a3 = fmaf(q.w, EXP2(-(v * v)), a3); }
        }
    }
    __syncthreads();  // sj consumed
    sredf[wv * 256 +       lane] = a0;
    sredf[wv * 256 +  64 + lane] = a1;
    sredf[wv * 256 + 128 + lane] = a2;
    sredf[wv * 256 + 192 + lane] = a3;
    __syncthreads();
    partial[y * nmax + ib * 256 + t] =
        sredf[t] + sredf[256 + t] + sredf[512 + t] + sredf[768 + t];

    // last-done block performs the finalize (deterministic result regardless of which)
    if (t == 0) {
        __threadfence();  // make this block's partial visible before the count
        int old = atomicAdd(done, 1);
        slast = (old == (int)(gridDim.x * gridDim.y) - 1) ? 1 : 0;
    }
    __syncthreads();
    if (slast) {
        __threadfence();  // acquire: all other blocks' partials now visible
        for (int i = t; i < n; i += BLK) {
            float p = 0.f;
            #pragma unroll
            for (int y2 = 0; y2 < YW; ++y2) p += partial[y2 * nmax + i];
            out[i] = logf(p + 1e-10f);
        }
    }
}

extern "C" void kernel_launch(void* const* d_in, const int* in_sizes, int n_in,
                              void* d_out, int out_size, void* d_ws, size_t ws_size,
                              hipStream_t stream) {
    const float* d = (const float*)d_in[0];
    const float* w = (const float*)d_in[1];
    float* out = (float*)d_out;
    const int n = in_sizes[0];

    const int nmax = ((n + 255) / 256) * 256;   // 12032 (multiple of 256; /16 window = 752)
    const int IB = nmax / 256;                  // 47

    // ws layout (float units):
    //   counts  int[YW*nmax]
    //   statsP  float4[YW]            (64 floats)
    //   ejwj    float2[nmax]          (2*nmax floats)
    //   partial float[YW*nmax]
    //   done    int
    float*  wsf     = (float*)d_ws;
    int*    counts  = (int*)wsf;
    float4* statsP  = (float4*)(wsf + YW * nmax);
    float2* ejwj    = (float2*)(wsf + YW * nmax + 64);
    float*  partial = wsf + YW * nmax + 64 + 2 * nmax;
    int*    done    = (int*)(wsf + 2 * YW * nmax + 64 + 2 * nmax);

    dim3 grid(IB, YW);
    count_k<<<grid, BLK, 0, stream>>>(d, w, counts, statsP, n, nmax);
    pick_k<<<1, 1024, 0, stream>>>(d, w, counts, statsP, ejwj, done, n, nmax);
    kdefin_k<<<grid, BLK, 0, stream>>>(ejwj, partial, out, done, n, nmax);
}

// Round 5
// 61.366 us; speedup vs baseline: 3.9981x; 1.3450x over previous
//
#include <hip/hip_runtime.h>
#include <math.h>

// Gaussian KDE, n=12000. 4 dispatches, no device atomics/fences, no memset.
//   1) count_k grid(47,16)x256: block = 256 i's (II=4/lane) x 752-j window.
//      counts[y*nmax+i] = packed (le<<16|lt); ib==0 blocks emit per-window
//      stats partials (S1,S2,Sd,Sd2).
//   2) pick_k  1x1024: sum 16 packed count partials -> 4 order stats; h, r, wsc;
//      writes pre-scaled ejwj[].
//   3) kde_k   grid(47,16)x256: partial[y*nmax+i] = sum_{j in win} w'_j*exp2(-(e_i-e_j)^2)
//   4) fin_k   47x256: out[i] = log(sum_y partial[y][i] + 1e-10)
// All accumulation orders fixed -> bit-deterministic across replays.

#define BLK 256
#define YW 16
#define MAXWIN 768

#if defined(__has_builtin)
#if __has_builtin(__builtin_amdgcn_exp2f)
#define EXP2(x) __builtin_amdgcn_exp2f(x)
#endif
#endif
#ifndef EXP2
#define EXP2(x) exp2f(x)
#endif

__global__ __launch_bounds__(BLK) void count_k(const float* __restrict__ d,
                                               const float* __restrict__ w,
                                               int* __restrict__ counts,
                                               float4* __restrict__ statsP,
                                               int n, int nmax) {
    __shared__ int smem[1024];          // phase1: float window[752]; phase2: combine
    __shared__ float4 sstat[4];
    const int t = threadIdx.x, ib = blockIdx.x, y = blockIdx.y;
    const int lane = t & 63, wv = t >> 6;
    const int WIN = nmax / YW;          // 752
    const int j0 = y * WIN;

    float* sd = (float*)smem;
    for (int idx = t; idx < WIN; idx += BLK) {
        int jg = j0 + idx;
        sd[idx] = (jg < n) ? d[jg] : __int_as_float(0x7f800000);  // +inf pad
    }
    const int i0 = ib * 256 + lane;
    const float di0 = (i0       < n) ? d[i0]       : 0.f;
    const float di1 = (i0 + 64  < n) ? d[i0 + 64]  : 0.f;
    const float di2 = (i0 + 128 < n) ? d[i0 + 128] : 0.f;
    const float di3 = (i0 + 192 < n) ? d[i0 + 192] : 0.f;
    __syncthreads();

    int lt0 = 0, le0 = 0, lt1 = 0, le1 = 0, lt2 = 0, le2 = 0, lt3 = 0, le3 = 0;
    {
        const float4* p4 = (const float4*)(sd + wv * (WIN >> 2));  // 188 floats/wave
        const int nq = WIN >> 4;  // 47
        for (int jj = 0; jj < nq; ++jj) {
            float4 q = p4[jj];
            lt0 += (q.x <  di0) + (q.y <  di0) + (q.z <  di0) + (q.w <  di0);
            le0 += (q.x <= di0) + (q.y <= di0) + (q.z <= di0) + (q.w <= di0);
            lt1 += (q.x <  di1) + (q.y <  di1) + (q.z <  di1) + (q.w <  di1);
            le1 += (q.x <= di1) + (q.y <= di1) + (q.z <= di1) + (q.w <= di1);
            lt2 += (q.x <  di2) + (q.y <  di2) + (q.z <  di2) + (q.w <  di2);
            le2 += (q.x <= di2) + (q.y <= di2) + (q.z <= di2) + (q.w <= di2);
            lt3 += (q.x <  di3) + (q.y <  di3) + (q.z <  di3) + (q.w <  di3);
            le3 += (q.x <= di3) + (q.y <= di3) + (q.z <= di3) + (q.w <= di3);
        }
    }
    float4 st = make_float4(0.f, 0.f, 0.f, 0.f);
    if (ib == 0) {   // per-window stats while sd still holds d
        for (int idx = t; idx < WIN; idx += BLK) {
            int jg = j0 + idx;
            if (jg < n) {
                float dv = sd[idx], wj = w[jg];
                st.x += wj; st.y += wj * wj; st.z += dv; st.w += dv * dv;
            }
        }
    }
    __syncthreads();
    smem[wv * 256 +       lane] = (le0 << 16) | lt0;
    smem[wv * 256 +  64 + lane] = (le1 << 16) | lt1;
    smem[wv * 256 + 128 + lane] = (le2 << 16) | lt2;
    smem[wv * 256 + 192 + lane] = (le3 << 16) | lt3;
    __syncthreads();
    counts[y * nmax + ib * 256 + t] =
        smem[t] + smem[256 + t] + smem[512 + t] + smem[768 + t];

    if (ib == 0) {
        for (int off = 32; off > 0; off >>= 1) {
            st.x += __shfl_down(st.x, off); st.y += __shfl_down(st.y, off);
            st.z += __shfl_down(st.z, off); st.w += __shfl_down(st.w, off);
        }
        if (lane == 0) sstat[wv] = st;
        __syncthreads();
        if (t == 0) {
            float4 a = sstat[0], b = sstat[1], c = sstat[2], e = sstat[3];
            statsP[y] = make_float4(a.x + b.x + c.x + e.x, a.y + b.y + c.y + e.y,
                                    a.z + b.z + c.z + e.z, a.w + b.w + c.w + e.w);
        }
    }
}

__global__ __launch_bounds__(1024) void pick_k(const float* __restrict__ d,
                                               const float* __restrict__ w,
                                               const int* __restrict__ counts,
                                               const float4* __restrict__ statsP,
                                               float2* __restrict__ ejwj,
                                               int n, int nmax) {
    __shared__ float sp[4];
    __shared__ float sparams[2];
    const int t = threadIdx.x;

    const double p25 = 0.25 * (double)(n - 1);
    const double p75 = 0.75 * (double)(n - 1);
    const int l25 = (int)p25, l75 = (int)p75;
    const int u25 = (l25 + 1 < n) ? l25 + 1 : l25;
    const int u75 = (l75 + 1 < n) ? l75 + 1 : l75;

    for (int i = t; i < n; i += 1024) {
        int c = 0;
        #pragma unroll
        for (int y = 0; y < YW; ++y) c += counts[y * nmax + i];
        int lt = c & 0xFFFF, le = c >> 16;   // fields <= n < 2^16: no cross-carry
        float dv = d[i];
        if (lt <= l25 && l25 < le) sp[0] = dv;
        if (lt <= u25 && u25 < le) sp[1] = dv;
        if (lt <= l75 && l75 < le) sp[2] = dv;
        if (lt <= u75 && u75 < le) sp[3] = dv;
    }
    __syncthreads();
    if (t == 0) {
        double S1 = 0, S2 = 0, Sd = 0, Sd2 = 0;
        for (int k = 0; k < YW; ++k) {
            float4 v = statsP[k];
            S1 += v.x; S2 += v.y; Sd += v.z; Sd2 += v.w;
        }
        double neff = S1 * S1 / S2;
        double var  = (Sd2 - Sd * Sd / (double)n) / ((double)n - 1.0);
        double sdev = sqrt(var);
        double f25 = p25 - (double)l25, f75 = p75 - (double)l75;
        double q25 = (double)sp[0] + f25 * ((double)sp[1] - (double)sp[0]);
        double q75 = (double)sp[2] + f75 * ((double)sp[3] - (double)sp[2]);
        double sig = fmin(sdev, (q75 - q25) / 1.34);
        double h = 0.9 * sig * pow(neff, -0.2);
        sparams[0] = (float)(sqrt(0.5 * 1.4426950408889634) / h);          // r
        sparams[1] = (float)(1.0 / (h * sqrt(6.283185307179586) * S1));    // wsc
    }
    __syncthreads();
    const float r = sparams[0], wsc = sparams[1];
    for (int j = t; j < nmax; j += 1024)
        ejwj[j] = (j < n) ? make_float2(d[j] * r, w[j] * wsc) : make_float2(0.f, 0.f);
}

__global__ __launch_bounds__(BLK) void kde_k(const float2* __restrict__ ejwj,
                                             float* __restrict__ partial,
                                             int n, int nmax) {
    __shared__ float2 sj[MAXWIN];    // 6 KB
    __shared__ float sredf[1024];    // 4 KB
    const int t = threadIdx.x, ib = blockIdx.x, y = blockIdx.y;
    const int lane = t & 63, wv = t >> 6;
    const int WIN = nmax / YW;       // 752
    const int j0 = y * WIN;

    for (int idx = t; idx < WIN; idx += BLK)
        sj[idx] = ejwj[j0 + idx];    // pads are (0,0): zero weight
    const int i0 = ib * 256 + lane;
    const float ei0 = ejwj[i0].x;
    const float ei1 = ejwj[i0 + 64].x;
    const float ei2 = ejwj[i0 + 128].x;
    const float ei3 = ejwj[i0 + 192].x;
    __syncthreads();

    float a0 = 0.f, a1 = 0.f, a2 = 0.f, a3 = 0.f;
    {
        const float4* pj = (const float4*)(sj + wv * (WIN >> 2));  // 188 float2/wave
        const int nq = WIN >> 3;  // 94 float4 = 188 j's
        for (int jj = 0; jj < nq; ++jj) {
            float4 q = pj[jj];  // (e_a, w_a, e_b, w_b)
            { float u = ei0 - q.x, v = ei0 - q.z;
              a0 = fmaf(q.y, EXP2(-(u * u)), a0); a0 = fmaf(q.w, EXP2(-(v * v)), a0); }
            { float u = ei1 - q.x, v = ei1 - q.z;
              a1 = fmaf(q.y, EXP2(-(u * u)), a1); a1 = fmaf(q.w, EXP2(-(v * v)), a1); }
            { float u = ei2 - q.x, v = ei2 - q.z;
              a2 = fmaf(q.y, EXP2(-(u * u)), a2); a2 = fmaf(q.w, EXP2(-(v * v)), a2); }
            { float u = ei3 - q.x, v = ei3 - q.z;
              a3 = fmaf(q.y, EXP2(-(u * u)), a3); a3 = fmaf(q.w, EXP2(-(v * v)), a3); }
        }
    }
    __syncthreads();
    sredf[wv * 256 +       lane] = a0;
    sredf[wv * 256 +  64 + lane] = a1;
    sredf[wv * 256 + 128 + lane] = a2;
    sredf[wv * 256 + 192 + lane] = a3;
    __syncthreads();
    partial[y * nmax + ib * 256 + t] =
        sredf[t] + sredf[256 + t] + sredf[512 + t] + sredf[768 + t];
}

__global__ __launch_bounds__(BLK) void fin_k(const float* __restrict__ partial,
                                             float* __restrict__ out, int n, int nmax) {
    int i = blockIdx.x * BLK + threadIdx.x;
    if (i < n) {
        float p = 0.f;
        #pragma unroll
        for (int y = 0; y < YW; ++y) p += partial[y * nmax + i];
        out[i] = logf(p + 1e-10f);
    }
}

extern "C" void kernel_launch(void* const* d_in, const int* in_sizes, int n_in,
                              void* d_out, int out_size, void* d_ws, size_t ws_size,
                              hipStream_t stream) {
    const float* d = (const float*)d_in[0];
    const float* w = (const float*)d_in[1];
    float* out = (float*)d_out;
    const int n = in_sizes[0];

    const int nmax = ((n + 255) / 256) * 256;   // 12032
    const int IB = nmax / 256;                  // 47

    // ws layout (float units): counts int[YW*nmax] | statsP float4[YW] |
    //                          ejwj float2[nmax] | partial float[YW*nmax]
    float*  wsf     = (float*)d_ws;
    int*    counts  = (int*)wsf;
    float4* statsP  = (float4*)(wsf + YW * nmax);
    float2* ejwj    = (float2*)(wsf + YW * nmax + 64);
    float*  partial = wsf + YW * nmax + 64 + 2 * nmax;

    dim3 grid(IB, YW);
    count_k<<<grid, BLK, 0, stream>>>(d, w, counts, statsP, n, nmax);
    pick_k<<<1, 1024, 0, stream>>>(d, w, counts, statsP, ejwj, n, nmax);
    kde_k<<<grid, BLK, 0, stream>>>(ejwj, partial, n, nmax);
    fin_k<<<IB, BLK, 0, stream>>>(partial, out, n, nmax);
}

// Round 6
// 60.332 us; speedup vs baseline: 4.0666x; 1.0171x over previous
//
#include <hip/hip_runtime.h>
#include <math.h>

// Gaussian KDE, n=12000. 3 dispatches:
//   1) sel_k  1x1024: stats sums + exact Q25/Q75 order stats via 3-level radix
//      select on monotone float keys (LDS-staged); computes h; writes ejwj[].
//   2) kde_k  grid(47,16)x256: partial[y*nmax+i] = sum_{j in win} w'_j*exp2(-(e_i-e_j)^2)
//   3) fin_k  47x256: out[i] = log(sum_y partial[y][i] + 1e-10)
// Integer LDS atomics only (order-independent) -> bit-deterministic.

#define BLK 256
#define YW 16
#define MAXWIN 768
#define MAXN 12032

#if defined(__has_builtin)
#if __has_builtin(__builtin_amdgcn_exp2f)
#define EXP2(x) __builtin_amdgcn_exp2f(x)
#endif
#endif
#ifndef EXP2
#define EXP2(x) exp2f(x)
#endif

__global__ __launch_bounds__(1024) void sel_k(const float* __restrict__ d,
                                              const float* __restrict__ w,
                                              float2* __restrict__ ejwj,
                                              int n, int nmax) {
    __shared__ unsigned int keys[MAXN];   // 48128 B
    __shared__ int hist[2048];            // 8 KB (hist -> inclusive cums in place)
    __shared__ int wtot[16];
    __shared__ int sfound[2];             // {bin, base-below-bin}
    __shared__ float4 sstat[16];
    __shared__ float sq[4];
    __shared__ float sparams[2];

    const int t = threadIdx.x, lane = t & 63, wid = t >> 6;

    // ---- pass 1: keys + stats partials ----
    float s1 = 0.f, s2 = 0.f, sd = 0.f, sd2 = 0.f;
    for (int i = t; i < n; i += 1024) {
        float dv = d[i], wv = w[i];
        s1 += wv; s2 += wv * wv; sd += dv; sd2 += dv * dv;
        unsigned u = __float_as_uint(dv);
        keys[i] = (u & 0x80000000u) ? ~u : (u | 0x80000000u);  // monotone key
    }
    for (int off = 32; off > 0; off >>= 1) {
        s1  += __shfl_down(s1,  off); s2  += __shfl_down(s2,  off);
        sd  += __shfl_down(sd,  off); sd2 += __shfl_down(sd2, off);
    }
    if (lane == 0) sstat[wid] = make_float4(s1, s2, sd, sd2);

    // ---- radix select 4 ranks ----
    const double p25 = 0.25 * (double)(n - 1);
    const double p75 = 0.75 * (double)(n - 1);
    const int l25 = (int)p25, l75 = (int)p75;
    const int u25 = (l25 + 1 < n) ? l25 + 1 : l25;
    const int u75 = (l75 + 1 < n) ? l75 + 1 : l75;
    const int targets[4] = {l25, u25, l75, u75};

    __syncthreads();

    for (int r = 0; r < 4; ++r) {
        const int k = targets[r];
        unsigned prefix = 0;
        int base = 0;
        for (int lvl = 0; lvl < 3; ++lvl) {
            const int shift = (lvl == 0) ? 21 : (lvl == 1) ? 10 : 0;
            const int bins  = (lvl == 2) ? 1024 : 2048;
            const unsigned mask = (unsigned)bins - 1u;
            for (int b = t; b < bins; b += 1024) hist[b] = 0;
            __syncthreads();
            for (int i = t; i < n; i += 1024) {
                unsigned key = keys[i];
                bool ok = (lvl == 0) ||
                          (lvl == 1 ? ((key >> 21) == prefix)
                                    : ((key >> 10) == prefix));
                if (ok) atomicAdd(&hist[(key >> shift) & mask], 1);
            }
            __syncthreads();
            // in-place inclusive scan of hist[0..bins)
            {
                const int e = bins >> 10;                 // 2 or 1 per thread
                const int b0 = t * e;
                int a0 = hist[b0];
                int a1 = (e == 2) ? hist[b0 + 1] : 0;
                int seg = a0 + a1;
                int v = seg;
                for (int off = 1; off < 64; off <<= 1) {
                    int u = __shfl_up(v, off);
                    if (lane >= off) v += u;
                }
                if (lane == 63) wtot[wid] = v;
                __syncthreads();
                if (t == 0) {
                    int acc = 0;
                    for (int q = 0; q < 16; ++q) { int tmp = wtot[q]; wtot[q] = acc; acc += tmp; }
                }
                __syncthreads();
                int excl = wtot[wid] + (v - seg);
                hist[b0] = excl + a0;
                if (e == 2) hist[b0 + 1] = excl + a0 + a1;
                __syncthreads();
            }
            // find bin containing local rank kk
            const int kk = k - base;
            for (int b = t; b < bins; b += 1024) {
                int incl = hist[b];
                int prev = b ? hist[b - 1] : 0;
                if (prev <= kk && kk < incl) { sfound[0] = b; sfound[1] = prev; }
            }
            __syncthreads();
            int b = sfound[0];
            base += sfound[1];
            prefix = (lvl == 0) ? (unsigned)b
                   : (lvl == 1) ? ((prefix << 11) | (unsigned)b)
                                : ((prefix << 10) | (unsigned)b);
            __syncthreads();
        }
        if (t == 0) {
            unsigned kf = prefix;  // full 32-bit key of rank-k element
            sq[r] = (kf & 0x80000000u) ? __uint_as_float(kf ^ 0x80000000u)
                                       : __uint_as_float(~kf);
        }
        __syncthreads();
    }

    // ---- h + scales ----
    if (t == 0) {
        double S1 = 0, S2 = 0, Sd = 0, Sd2 = 0;
        for (int q = 0; q < 16; ++q) {
            float4 v = sstat[q];
            S1 += v.x; S2 += v.y; Sd += v.z; Sd2 += v.w;
        }
        double neff = S1 * S1 / S2;
        double var  = (Sd2 - Sd * Sd / (double)n) / ((double)n - 1.0);
        double sdev = sqrt(var);
        double f25 = p25 - (double)l25, f75 = p75 - (double)l75;
        double q25 = (double)sq[0] + f25 * ((double)sq[1] - (double)sq[0]);
        double q75 = (double)sq[2] + f75 * ((double)sq[3] - (double)sq[2]);
        double sig = fmin(sdev, (q75 - q25) / 1.34);
        double h = 0.9 * sig * pow(neff, -0.2);
        sparams[0] = (float)(sqrt(0.5 * 1.4426950408889634) / h);          // r
        sparams[1] = (float)(1.0 / (h * sqrt(6.283185307179586) * S1));    // wsc
    }
    __syncthreads();
    const float rr = sparams[0], wsc = sparams[1];
    for (int j = t; j < nmax; j += 1024)
        ejwj[j] = (j < n) ? make_float2(d[j] * rr, w[j] * wsc) : make_float2(0.f, 0.f);
}

__global__ __launch_bounds__(BLK) void kde_k(const float2* __restrict__ ejwj,
                                             float* __restrict__ partial,
                                             int n, int nmax) {
    __shared__ float2 sj[MAXWIN];    // 6 KB
    __shared__ float sredf[1024];    // 4 KB
    const int t = threadIdx.x, ib = blockIdx.x, y = blockIdx.y;
    const int lane = t & 63, wv = t >> 6;
    const int WIN = nmax / YW;       // 752
    const int j0 = y * WIN;

    for (int idx = t; idx < WIN; idx += BLK)
        sj[idx] = ejwj[j0 + idx];    // pads are (0,0): zero weight
    const int i0 = ib * 256 + lane;
    const float ei0 = ejwj[i0].x;
    const float ei1 = ejwj[i0 + 64].x;
    const float ei2 = ejwj[i0 + 128].x;
    const float ei3 = ejwj[i0 + 192].x;
    __syncthreads();

    float a0 = 0.f, a1 = 0.f, a2 = 0.f, a3 = 0.f;
    {
        const float4* pj = (const float4*)(sj + wv * (WIN >> 2));  // 188 float2/wave
        const int nq = WIN >> 3;  // 94 float4 = 188 j's
        for (int jj = 0; jj < nq; ++jj) {
            float4 q = pj[jj];  // (e_a, w_a, e_b, w_b)
            { float u = ei0 - q.x, v = ei0 - q.z;
              a0 = fmaf(q.y, EXP2(-(u * u)), a0); a0 = fmaf(q.w, EXP2(-(v * v)), a0); }
            { float u = ei1 - q.x, v = ei1 - q.z;
              a1 = fmaf(q.y, EXP2(-(u * u)), a1); a1 = fmaf(q.w, EXP2(-(v * v)), a1); }
            { float u = ei2 - q.x, v = ei2 - q.z;
              a2 = fmaf(q.y, EXP2(-(u * u)), a2); a2 = fmaf(q.w, EXP2(-(v * v)), a2); }
            { float u = ei3 - q.x, v = ei3 - q.z;
              a3 = fmaf(q.y, EXP2(-(u * u)), a3); a3 = fmaf(q.w, EXP2(-(v * v)), a3); }
        }
    }
    __syncthreads();
    sredf[wv * 256 +       lane] = a0;
    sredf[wv * 256 +  64 + lane] = a1;
    sredf[wv * 256 + 128 + lane] = a2;
    sredf[wv * 256 + 192 + lane] = a3;
    __syncthreads();
    partial[y * nmax + ib * 256 + t] =
        sredf[t] + sredf[256 + t] + sredf[512 + t] + sredf[768 + t];
}

__global__ __launch_bounds__(BLK) void fin_k(const float* __restrict__ partial,
                                             float* __restrict__ out, int n, int nmax) {
    int i = blockIdx.x * BLK + threadIdx.x;
    if (i < n) {
        float p = 0.f;
        #pragma unroll
        for (int y = 0; y < YW; ++y) p += partial[y * nmax + i];
        out[i] = logf(p + 1e-10f);
    }
}

extern "C" void kernel_launch(void* const* d_in, const int* in_sizes, int n_in,
                              void* d_out, int out_size, void* d_ws, size_t ws_size,
                              hipStream_t stream) {
    const float* d = (const float*)d_in[0];
    const float* w = (const float*)d_in[1];
    float* out = (float*)d_out;
    const int n = in_sizes[0];

    const int nmax = ((n + 255) / 256) * 256;   // 12032
    const int IB = nmax / 256;                  // 47

    // ws layout (float units): ejwj float2[nmax] | partial float[YW*nmax]
    float*  wsf     = (float*)d_ws;
    float2* ejwj    = (float2*)wsf;
    float*  partial = wsf + 2 * nmax;

    sel_k<<<1, 1024, 0, stream>>>(d, w, ejwj, n, nmax);
    dim3 grid(IB, YW);
    kde_k<<<grid, BLK, 0, stream>>>(ejwj, partial, n, nmax);
    fin_k<<<IB, BLK, 0, stream>>>(partial, out, n, nmax);
}

// Round 7
// 49.818 us; speedup vs baseline: 4.9249x; 1.2110x over previous
//
#include <hip/hip_runtime.h>
#include <math.h>

// Gaussian KDE, n=12000. 3 dispatches (~7us/dispatch graph overhead measured):
//   1) sel_k  1x1024: stats sums + exact Q25/Q75 order stats via radix select
//      (level-0 hist built ONCE, 4-way privatized; cumL1/cumL2 prefix-reuse);
//      computes h; writes pre-scaled ejwj[].
//   2) kde_k  grid(47,16)x256: partial[y*nmax+i] = sum_{j in win} w'_j*exp2(-(e_i-e_j)^2)
//   3) fin_k  47x256: out[i] = log(sum_y partial[y][i] + 1e-10)
// Integer LDS atomics only (order-independent) -> bit-deterministic.

#define BLK 256
#define YW 16
#define MAXWIN 768
#define MAXN 12032

#if defined(__has_builtin)
#if __has_builtin(__builtin_amdgcn_exp2f)
#define EXP2(x) __builtin_amdgcn_exp2f(x)
#endif
#endif
#ifndef EXP2
#define EXP2(x) exp2f(x)
#endif

__device__ __forceinline__ void scan_cum(int* hist, int* cum, int bins, int* wtot) {
    // inclusive scan hist[0..bins) -> cum[0..bins). bins in {1024, 2048}. 1024 thr.
    const int t = threadIdx.x, lane = t & 63, wid = t >> 6;
    const int e = bins >> 10;            // 1 or 2 bins per thread
    const int b0 = t * e;
    int a0 = hist[b0];
    int a1 = (e == 2) ? hist[b0 + 1] : 0;
    int seg = a0 + a1, v = seg;
    for (int off = 1; off < 64; off <<= 1) {
        int u = __shfl_up(v, off);
        if (lane >= off) v += u;
    }
    if (lane == 63) wtot[wid] = v;
    __syncthreads();
    if (t == 0) {
        int acc = 0;
        for (int q = 0; q < 16; ++q) { int tmp = wtot[q]; wtot[q] = acc; acc += tmp; }
    }
    __syncthreads();
    int excl = wtot[wid] + (v - seg);
    cum[b0] = excl + a0;
    if (e == 2) cum[b0 + 1] = excl + a0 + a1;
    __syncthreads();
}

__device__ __forceinline__ void findbin(const int* cum, int bins, int kk, int* sout) {
    __syncthreads();   // protect sout from previous readers
    for (int b = threadIdx.x; b < bins; b += 1024) {
        int incl = cum[b], prev = b ? cum[b - 1] : 0;
        if (prev <= kk && kk < incl) { sout[0] = b; sout[1] = prev; }
    }
    __syncthreads();
}

__global__ __launch_bounds__(1024) void sel_k(const float* __restrict__ d,
                                              const float* __restrict__ w,
                                              float2* __restrict__ ejwj,
                                              int n, int nmax) {
    __shared__ unsigned int keys[MAXN];   // 48.1 KB
    __shared__ int hist[4][2048];         // 32 KB (4-way privatized L0; [0] reused L1/L2)
    __shared__ int cumL0[2048];           // 8 KB
    __shared__ int cumL1[2048];           // 8 KB
    __shared__ int cumL2[1024];           // 4 KB
    __shared__ int wtot[16];
    __shared__ int sbin[2];
    __shared__ float4 sstat[16];
    __shared__ float sq[4];
    __shared__ float sparams[2];

    const int t = threadIdx.x, lane = t & 63, wid = t >> 6;
    int* hist0 = hist[0];

    // ---- pass 1: keys + stats partials; zero L0 hist ----
    for (int b = t; b < 4 * 2048; b += 1024) ((int*)hist)[b] = 0;
    float s1 = 0.f, s2 = 0.f, sd = 0.f, sd2 = 0.f;
    for (int i = t; i < n; i += 1024) {
        float dv = d[i], wv = w[i];
        s1 += wv; s2 += wv * wv; sd += dv; sd2 += dv * dv;
        unsigned u = __float_as_uint(dv);
        keys[i] = (u & 0x80000000u) ? ~u : (u | 0x80000000u);  // monotone key
    }
    for (int off = 32; off > 0; off >>= 1) {
        s1  += __shfl_down(s1,  off); s2  += __shfl_down(s2,  off);
        sd  += __shfl_down(sd,  off); sd2 += __shfl_down(sd2, off);
    }
    if (lane == 0) sstat[wid] = make_float4(s1, s2, sd, sd2);
    __syncthreads();

    // ---- L0 histogram (once, 4-way privatized over top-11 bits) ----
    {
        int* hc = hist[wid >> 2];
        for (int i = t; i < n; i += 1024) atomicAdd(&hc[keys[i] >> 21], 1);
    }
    __syncthreads();
    for (int b = t; b < 2048; b += 1024)
        hist0[b] = hist[0][b] + hist[1][b] + hist[2][b] + hist[3][b];
    __syncthreads();
    scan_cum(hist0, cumL0, 2048, wtot);

    // ---- select 4 ranks with prefix-reuse ----
    const double p25 = 0.25 * (double)(n - 1);
    const double p75 = 0.75 * (double)(n - 1);
    const int l25 = (int)p25, l75 = (int)p75;
    const int u25 = (l25 + 1 < n) ? l25 + 1 : l25;
    const int u75 = (l75 + 1 < n) ? l75 + 1 : l75;
    const int targets[4] = {l25, u25, l75, u75};

    int pL1 = -1, pL2 = -1;   // uniform across threads
    for (int r = 0; r < 4; ++r) {
        const int k = targets[r];
        findbin(cumL0, 2048, k, sbin);
        const int b0v = sbin[0], base0 = sbin[1];

        if (b0v != pL1) {   // build cumL1 for prefix b0v (bits 20..10)
            for (int b = t; b < 2048; b += 1024) hist0[b] = 0;
            __syncthreads();
            for (int i = t; i < n; i += 1024) {
                unsigned key = keys[i];
                if ((int)(key >> 21) == b0v) atomicAdd(&hist0[(key >> 10) & 0x7FF], 1);
            }
            __syncthreads();
            scan_cum(hist0, cumL1, 2048, wtot);
            pL1 = b0v; pL2 = -1;
        }
        findbin(cumL1, 2048, k - base0, sbin);
        const int b1v = sbin[0];
        const int base1 = base0 + sbin[1];
        const int pfx = (b0v << 11) | b1v;

        if (pfx != pL2) {   // build cumL2 for prefix pfx (bits 9..0)
            for (int b = t; b < 1024; b += 1024) hist0[b] = 0;
            __syncthreads();
            for (int i = t; i < n; i += 1024) {
                unsigned key = keys[i];
                if ((int)(key >> 10) == pfx) atomicAdd(&hist0[key & 0x3FF], 1);
            }
            __syncthreads();
            scan_cum(hist0, cumL2, 1024, wtot);
            pL2 = pfx;
        }
        findbin(cumL2, 1024, k - base1, sbin);
        if (t == 0) {
            unsigned kf = ((unsigned)pfx << 10) | (unsigned)sbin[0];
            sq[r] = (kf & 0x80000000u) ? __uint_as_float(kf ^ 0x80000000u)
                                       : __uint_as_float(~kf);
        }
    }
    __syncthreads();

    // ---- h + scales ----
    if (t == 0) {
        double S1 = 0, S2 = 0, Sd = 0, Sd2 = 0;
        for (int q = 0; q < 16; ++q) {
            float4 v = sstat[q];
            S1 += v.x; S2 += v.y; Sd += v.z; Sd2 += v.w;
        }
        double neff = S1 * S1 / S2;
        double var  = (Sd2 - Sd * Sd / (double)n) / ((double)n - 1.0);
        double sdev = sqrt(var);
        double f25 = p25 - (double)l25, f75 = p75 - (double)l75;
        double q25 = (double)sq[0] + f25 * ((double)sq[1] - (double)sq[0]);
        double q75 = (double)sq[2] + f75 * ((double)sq[3] - (double)sq[2]);
        double sig = fmin(sdev, (q75 - q25) / 1.34);
        double h = 0.9 * sig * pow(neff, -0.2);
        sparams[0] = (float)(sqrt(0.5 * 1.4426950408889634) / h);          // r
        sparams[1] = (float)(1.0 / (h * sqrt(6.283185307179586) * S1));    // wsc
    }
    __syncthreads();
    const float rr = sparams[0], wsc = sparams[1];
    for (int j = t; j < nmax; j += 1024)
        ejwj[j] = (j < n) ? make_float2(d[j] * rr, w[j] * wsc) : make_float2(0.f, 0.f);
}

__global__ __launch_bounds__(BLK) void kde_k(const float2* __restrict__ ejwj,
                                             float* __restrict__ partial,
                                             int n, int nmax) {
    __shared__ float2 sj[MAXWIN];    // 6 KB
    __shared__ float sredf[1024];    // 4 KB
    const int t = threadIdx.x, ib = blockIdx.x, y = blockIdx.y;
    const int lane = t & 63, wv = t >> 6;
    const int WIN = nmax / YW;       // 752
    const int j0 = y * WIN;

    // stage window via float4 (2 ejwj per load)
    for (int idx = t; idx < (WIN >> 1); idx += BLK)
        ((float4*)sj)[idx] = ((const float4*)(ejwj + j0))[idx];
    const int i0 = ib * 256 + lane;
    const float ei0 = ejwj[i0].x;
    const float ei1 = ejwj[i0 + 64].x;
    const float ei2 = ejwj[i0 + 128].x;
    const float ei3 = ejwj[i0 + 192].x;
    __syncthreads();

    float a0 = 0.f, a1 = 0.f, a2 = 0.f, a3 = 0.f;
    {
        const float4* pj = (const float4*)(sj + wv * (WIN >> 2));  // 188 float2/wave
        const int nq = WIN >> 3;  // 94 float4 = 188 j's
        for (int jj = 0; jj < nq; ++jj) {
            float4 q = pj[jj];  // (e_a, w_a, e_b, w_b)
            { float u = ei0 - q.x, v = ei0 - q.z;
              a0 = fmaf(q.y, EXP2(-(u * u)), a0); a0 = fmaf(q.w, EXP2(-(v * v)), a0); }
            { float u = ei1 - q.x, v = ei1 - q.z;
              a1 = fmaf(q.y, EXP2(-(u * u)), a1); a1 = fmaf(q.w, EXP2(-(v * v)), a1); }
            { float u = ei2 - q.x, v = ei2 - q.z;
              a2 = fmaf(q.y, EXP2(-(u * u)), a2); a2 = fmaf(q.w, EXP2(-(v * v)), a2); }
            { float u = ei3 - q.x, v = ei3 - q.z;
              a3 = fmaf(q.y, EXP2(-(u * u)), a3); a3 = fmaf(q.w, EXP2(-(v * v)), a3); }
        }
    }
    __syncthreads();
    sredf[wv * 256 +       lane] = a0;
    sredf[wv * 256 +  64 + lane] = a1;
    sredf[wv * 256 + 128 + lane] = a2;
    sredf[wv * 256 + 192 + lane] = a3;
    __syncthreads();
    partial[y * nmax + ib * 256 + t] =
        sredf[t] + sredf[256 + t] + sredf[512 + t] + sredf[768 + t];
}

__global__ __launch_bounds__(BLK) void fin_k(const float* __restrict__ partial,
                                             float* __restrict__ out, int n, int nmax) {
    int i = blockIdx.x * BLK + threadIdx.x;
    if (i < n) {
        float p = 0.f;
        #pragma unroll
        for (int y = 0; y < YW; ++y) p += partial[y * nmax + i];
        out[i] = logf(p + 1e-10f);
    }
}

extern "C" void kernel_launch(void* const* d_in, const int* in_sizes, int n_in,
                              void* d_out, int out_size, void* d_ws, size_t ws_size,
                              hipStream_t stream) {
    const float* d = (const float*)d_in[0];
    const float* w = (const float*)d_in[1];
    float* out = (float*)d_out;
    const int n = in_sizes[0];

    const int nmax = ((n + 255) / 256) * 256;   // 12032
    const int IB = nmax / 256;                  // 47

    // ws layout (float units): ejwj float2[nmax] | partial float[YW*nmax]
    float*  wsf     = (float*)d_ws;
    float2* ejwj    = (float2*)wsf;
    float*  partial = wsf + 2 * nmax;

    sel_k<<<1, 1024, 0, stream>>>(d, w, ejwj, n, nmax);
    dim3 grid(IB, YW);
    kde_k<<<grid, BLK, 0, stream>>>(ejwj, partial, n, nmax);
    fin_k<<<IB, BLK, 0, stream>>>(partial, out, n, nmax);
}